// Round 6
// baseline (1864.660 us; speedup 1.0000x reference)
//
#include <hip/hip_runtime.h>

// ---------------------------------------------------------------------------
// MaskedTransformerEmbeddingCosine on MI355X (gfx950)
// R5: GEMM K-loop restructured to 3-buffer / 2-ahead prefetch with raw
//     "s_waitcnt vmcnt(N); s_barrier" (no compiler fence -> no vmcnt(0)
//     drain at the barrier; prefetched tiles stay in flight across it).
// ---------------------------------------------------------------------------

#define LSEQ   1024
#define DMODEL 640
#define NHEAD  10
#define DHEAD  64
#define NLAYER 6
#define BDIM   8
#define FDIM   1280
#define MROWS  (BDIM * LSEQ)

typedef __attribute__((ext_vector_type(8))) _Float16 half8;
typedef __attribute__((ext_vector_type(4))) float    floatx4;

__device__ __forceinline__ void async_copy16(const void* g, void* l) {
  __builtin_amdgcn_global_load_lds(
      (const __attribute__((address_space(1))) void*)g,
      (__attribute__((address_space(3))) void*)l, 16, 0, 0);
}

// ---------------------------------------------------------------------------
// C = A(M,:) @ B(N,:)^T + bias [+ res] [relu]; row stride ld, K per z-slice.
// 128x128 tile, 4 waves each 64x64 (4x4 of 16x16x32), BK=32.
// 3 LDS buffers, 2 tiles ahead: iter i waits vmcnt(4) (own t_i loads done,
// t_{i+1}'s 4 still in flight) + s_barrier (cross-wave: each wave verified
// its own t_i loads pre-barrier), issues t_{i+2} into buf (i+2)%3 (all waves
// finished reading it during compute i-1, which precedes barrier i).
// ---------------------------------------------------------------------------
template <bool RELU, bool RESADD, bool SPLITK>
__global__ __launch_bounds__(256) void gemm_bt(const _Float16* __restrict__ A,
                                               const _Float16* __restrict__ Bw,
                                               const float* __restrict__ bias,
                                               const _Float16* __restrict__ res,
                                               _Float16* __restrict__ Cout,
                                               int M, int N, int K, int ld) {
  __shared__ _Float16 As[3][128 * 32];
  __shared__ _Float16 Bs[3][128 * 32];
  const int m0 = blockIdx.x * 128, n0 = blockIdx.y * 128;
  const int kz = SPLITK ? blockIdx.z : 0;
  const int tid = threadIdx.x;
  const int w = tid >> 6, lane = tid & 63;
  const int quad = lane >> 4, l16 = lane & 15;
  const int wm = w >> 1, wn = w & 1;

  floatx4 acc[4][4];
#pragma unroll
  for (int i = 0; i < 4; i++)
#pragma unroll
    for (int j = 0; j < 4; j++) acc[i][j] = (floatx4){0.f, 0.f, 0.f, 0.f};

  // staging: lane -> row w*16+(lane>>2), k-chunk xor-swizzled within the row
  const int arow = w * 16 + (lane >> 2);
  const int kswz = ((lane & 3) ^ ((lane >> 3) & 3)) * 8;
  const _Float16* ag = A + (size_t)(m0 + arow) * ld + kz * K + kswz;
  const _Float16* bg = Bw + (size_t)(n0 + arow) * ld + kz * K + kswz;
  const size_t krows = (size_t)64 * ld;
  const int lofs0 = (w * 16) * 32;
  const int lofs1 = (64 + w * 16) * 32;

  // fragment-read: row l16, chunk quad lives at slot quad^((l16>>1)&3)
  const int fro = l16 * 32 + ((quad ^ ((l16 >> 1) & 3)) * 8);

  const int nIter = K >> 5;
  // prologue: t0 -> buf0, t1 -> buf1 (4 loads each per wave)
  async_copy16(ag, &As[0][lofs0]);
  async_copy16(ag + krows, &As[0][lofs1]);
  async_copy16(bg, &Bs[0][lofs0]);
  async_copy16(bg + krows, &Bs[0][lofs1]);
  ag += 32; bg += 32;
  if (nIter > 1) {
    async_copy16(ag, &As[1][lofs0]);
    async_copy16(ag + krows, &As[1][lofs1]);
    async_copy16(bg, &Bs[1][lofs0]);
    async_copy16(bg + krows, &Bs[1][lofs1]);
    ag += 32; bg += 32;
  }

  int cur = 0;
  for (int i = 0; i < nIter; i++) {
    if (i + 1 < nIter)
      asm volatile("s_waitcnt vmcnt(4)\n\ts_barrier" ::: "memory");
    else
      asm volatile("s_waitcnt vmcnt(0)\n\ts_barrier" ::: "memory");
    if (i + 2 < nIter) {
      int nb = cur + 2; if (nb >= 3) nb -= 3;
      async_copy16(ag, &As[nb][lofs0]);
      async_copy16(ag + krows, &As[nb][lofs1]);
      async_copy16(bg, &Bs[nb][lofs0]);
      async_copy16(bg + krows, &Bs[nb][lofs1]);
      ag += 32; bg += 32;
    }
    const _Float16* as = As[cur];
    const _Float16* bs = Bs[cur];
    half8 af[4], bf[4];
#pragma unroll
    for (int mt = 0; mt < 4; mt++)
      af[mt] = *(const half8*)&as[(wm * 64 + mt * 16) * 32 + fro];
#pragma unroll
    for (int nt = 0; nt < 4; nt++)
      bf[nt] = *(const half8*)&bs[(wn * 64 + nt * 16) * 32 + fro];
#pragma unroll
    for (int mt = 0; mt < 4; mt++)
#pragma unroll
      for (int nt = 0; nt < 4; nt++)
        acc[mt][nt] = __builtin_amdgcn_mfma_f32_16x16x32_f16(af[mt], bf[nt], acc[mt][nt], 0, 0, 0);
    cur = (cur == 2) ? 0 : cur + 1;
  }

  const bool lead = (!SPLITK) || (kz == 0);
  _Float16* outp = Cout + (SPLITK ? (size_t)kz * ((size_t)M * N) : 0);
  float bv[4];
#pragma unroll
  for (int nt = 0; nt < 4; nt++)
    bv[nt] = lead ? bias[n0 + wn * 64 + nt * 16 + l16] : 0.f;
#pragma unroll
  for (int mt = 0; mt < 4; mt++) {
#pragma unroll
    for (int reg = 0; reg < 4; reg++) {
      const int row = m0 + wm * 64 + mt * 16 + quad * 4 + reg;
#pragma unroll
      for (int nt = 0; nt < 4; nt++) {
        const int col = n0 + wn * 64 + nt * 16 + l16;
        float v = acc[mt][nt][reg] + bv[nt];
        if (RESADD) { if (lead) v += (float)res[(size_t)row * N + col]; }
        if (RELU) v = fmaxf(v, 0.f);
        outp[(size_t)row * N + col] = (_Float16)v;
      }
    }
  }
}

// ---------------------------------------------------------------------------
// Banded attention: one block per (64-query tile, head, row-batch of 1024).
// ---------------------------------------------------------------------------
__global__ __launch_bounds__(256) void attn_kernel(const _Float16* __restrict__ qkv,
                                                   _Float16* __restrict__ o) {
  __shared__ _Float16 Qs[64 * 72];
  __shared__ _Float16 KP[192 * 72];   // K tiles; later reused as P (64 x 200)
  __shared__ _Float16 Vt[64 * 200];   // V transposed
  const int qb = blockIdx.x, h = blockIdx.y, b = blockIdx.z;
  const int q0 = qb * 64;
  const int kc0 = (q0 - 64 > 0) ? q0 - 64 : 0;
  const int kend = (q0 + 128 < LSEQ) ? q0 + 128 : LSEQ;
  const int cnt = kend - kc0;
  const int tid = threadIdx.x;

  for (int c = tid; c < 512; c += 256) {
    const int row = c >> 3, ch = c & 7;
    *(uint4*)&Qs[row * 72 + ch * 8] =
        *(const uint4*)(qkv + (size_t)(b * LSEQ + q0 + row) * (3 * DMODEL) + h * DHEAD + ch * 8);
  }
  for (int c = tid; c < 1536; c += 256) {
    const int row = c >> 3, ch = c & 7;
    uint4 v = {0u, 0u, 0u, 0u};
    if (row < cnt)
      v = *(const uint4*)(qkv + (size_t)(b * LSEQ + kc0 + row) * (3 * DMODEL) + DMODEL + h * DHEAD + ch * 8);
    *(uint4*)&KP[row * 72 + ch * 8] = v;
  }
  for (int c = tid; c < 1536; c += 256) {
    const int row = c >> 3, ch = c & 7;
    uint4 v = {0u, 0u, 0u, 0u};
    if (row < cnt)
      v = *(const uint4*)(qkv + (size_t)(b * LSEQ + kc0 + row) * (3 * DMODEL) + 2 * DMODEL + h * DHEAD + ch * 8);
    _Float16 tmp[8];
    *(uint4*)tmp = v;
#pragma unroll
    for (int jj = 0; jj < 8; jj++) Vt[(ch * 8 + jj) * 200 + row] = tmp[jj];
  }
  __syncthreads();

  const int w = tid >> 6, lane = tid & 63, quad = lane >> 4, l16 = lane & 15;

  floatx4 sacc[12];
#pragma unroll
  for (int i = 0; i < 12; i++) sacc[i] = (floatx4){0.f, 0.f, 0.f, 0.f};
#pragma unroll
  for (int ks = 0; ks < 2; ks++) {
    const half8 qf = *(const half8*)&Qs[(w * 16 + l16) * 72 + ks * 32 + quad * 8];
#pragma unroll
    for (int nt = 0; nt < 12; nt++) {
      const half8 kf = *(const half8*)&KP[(nt * 16 + l16) * 72 + ks * 32 + quad * 8];
      sacc[nt] = __builtin_amdgcn_mfma_f32_16x16x32_f16(qf, kf, sacc[nt], 0, 0, 0);
    }
  }
  __syncthreads();

#pragma unroll
  for (int r = 0; r < 4; r++) {
    const int qi = q0 + w * 16 + quad * 4 + r;
    float sv[12];
    float m = -1e30f;
#pragma unroll
    for (int nt = 0; nt < 12; nt++) {
      const int key = kc0 + nt * 16 + l16;
      const bool ok = (key >= qi - 64) && (key <= qi + 64) && (key < LSEQ);
      const float s = ok ? sacc[nt][r] * 0.125f : -1e30f;
      sv[nt] = s;
      m = fmaxf(m, s);
    }
#pragma unroll
    for (int d = 1; d < 16; d <<= 1) m = fmaxf(m, __shfl_xor(m, d));
    float sum = 0.f;
#pragma unroll
    for (int nt = 0; nt < 12; nt++) {
      const float p = __expf(sv[nt] - m);
      sv[nt] = p;
      sum += p;
    }
#pragma unroll
    for (int d = 1; d < 16; d <<= 1) sum += __shfl_xor(sum, d);
    const float inv = 1.f / sum;
    _Float16* Pr = &KP[(w * 16 + quad * 4 + r) * 200];
#pragma unroll
    for (int nt = 0; nt < 12; nt++) Pr[nt * 16 + l16] = (_Float16)(sv[nt] * inv);
  }
  __syncthreads();

  floatx4 oacc[4];
#pragma unroll
  for (int i = 0; i < 4; i++) oacc[i] = (floatx4){0.f, 0.f, 0.f, 0.f};
#pragma unroll
  for (int ks = 0; ks < 6; ks++) {
    const half8 pf = *(const half8*)&KP[(w * 16 + l16) * 200 + ks * 32 + quad * 8];
#pragma unroll
    for (int nt = 0; nt < 4; nt++) {
      const half8 vf = *(const half8*)&Vt[(nt * 16 + l16) * 200 + ks * 32 + quad * 8];
      oacc[nt] = __builtin_amdgcn_mfma_f32_16x16x32_f16(pf, vf, oacc[nt], 0, 0, 0);
    }
  }
#pragma unroll
  for (int nt = 0; nt < 4; nt++)
#pragma unroll
    for (int reg = 0; reg < 4; reg++) {
      const int row = q0 + w * 16 + quad * 4 + reg;
      const int col = h * DHEAD + nt * 16 + l16;
      o[(size_t)(b * LSEQ + row) * DMODEL + col] = (_Float16)oacc[nt][reg];
    }
}

// ---------------------------------------------------------------------------
// h = LayerNorm(s0 + s1) — fp16 split-K partials in, fp16 out. One wave/row.
// ---------------------------------------------------------------------------
__global__ __launch_bounds__(256) void ln_res2_kernel(const _Float16* __restrict__ s0,
                                                      const _Float16* __restrict__ s1,
                                                      const float* __restrict__ g,
                                                      const float* __restrict__ bta,
                                                      _Float16* __restrict__ hh) {
  const int row = blockIdx.x * 4 + (threadIdx.x >> 6);
  const int lane = threadIdx.x & 63;
  const _Float16* p0 = s0 + (size_t)row * DMODEL;
  const _Float16* p1 = s1 + (size_t)row * DMODEL;
  float v[10], s = 0.f, ss = 0.f;
#pragma unroll
  for (int i = 0; i < 10; i++) {
    const float x = (float)p0[lane + 64 * i] + (float)p1[lane + 64 * i];
    v[i] = x; s += x; ss += x * x;
  }
#pragma unroll
  for (int d = 1; d < 64; d <<= 1) { s += __shfl_xor(s, d); ss += __shfl_xor(ss, d); }
  const float mean = s * (1.f / DMODEL);
  const float var = ss * (1.f / DMODEL) - mean * mean;
  const float rstd = rsqrtf(var + 1e-5f);
#pragma unroll
  for (int i = 0; i < 10; i++) {
    const int d = lane + 64 * i;
    hh[(size_t)row * DMODEL + d] = (_Float16)((v[i] - mean) * rstd * g[d] + bta[d]);
  }
}

__global__ void cvt_kernel(const float* __restrict__ s, _Float16* __restrict__ d, int n) {
  int i = blockIdx.x * blockDim.x + threadIdx.x;
  const int stride = gridDim.x * blockDim.x;
  for (; i < n; i += stride) d[i] = (_Float16)s[i];
}

__global__ void zero_kernel(float* __restrict__ p, int n) {
  const int i = blockIdx.x * blockDim.x + threadIdx.x;
  if (i < n) p[i] = 0.f;
}

__global__ void pool_kernel(const _Float16* __restrict__ h, float* __restrict__ pooled) {
  const int b = blockIdx.x, chunk = blockIdx.y;  // 32 rows per chunk
  for (int d = threadIdx.x; d < DMODEL; d += 256) {
    float s = 0.f;
    const _Float16* p = h + ((size_t)b * LSEQ + chunk * 32) * DMODEL + d;
#pragma unroll 4
    for (int l = 0; l < 32; l++) s += (float)p[(size_t)l * DMODEL];
    atomicAdd(&pooled[b * DMODEL + d], s);
  }
}

__global__ void lnvec_kernel(const float* __restrict__ pooled, const float* __restrict__ g,
                             const float* __restrict__ bta, float* __restrict__ eln) {
  const int b = blockIdx.x, lane = threadIdx.x;  // 64 threads
  float v[10], s = 0.f, ss = 0.f;
#pragma unroll
  for (int i = 0; i < 10; i++) {
    const float x = pooled[b * DMODEL + lane + 64 * i];
    v[i] = x; s += x; ss += x * x;
  }
#pragma unroll
  for (int d = 1; d < 64; d <<= 1) { s += __shfl_xor(s, d); ss += __shfl_xor(ss, d); }
  const float mean = s * (1.f / DMODEL);
  const float var = ss * (1.f / DMODEL) - mean * mean;
  const float rstd = rsqrtf(var + 1e-5f);
#pragma unroll
  for (int i = 0; i < 10; i++) {
    const int d = lane + 64 * i;
    eln[b * DMODEL + d] = (v[i] - mean) * rstd * g[d] + bta[d];
  }
}

// one wave per output element
__global__ __launch_bounds__(256) void embed_kernel(const float* __restrict__ eln,
                                                    const float* __restrict__ We,
                                                    const float* __restrict__ be,
                                                    float* __restrict__ e) {
  const int gw = (blockIdx.x << 2) + (threadIdx.x >> 6);
  const int lane = threadIdx.x & 63;
  const int b = gw / DMODEL, n = gw % DMODEL;
  const float* wr = We + (size_t)n * DMODEL;
  const float* er = eln + (size_t)b * DMODEL;
  float s = 0.f;
#pragma unroll
  for (int i = 0; i < 10; i++) s += wr[lane + 64 * i] * er[lane + 64 * i];
#pragma unroll
  for (int d = 1; d < 64; d <<= 1) s += __shfl_xor(s, d);
  if (lane == 0) e[(size_t)b * DMODEL + n] = fmaxf(s + be[n], 0.f);
}

__global__ void cosine_kernel(const float* __restrict__ ex, const float* __restrict__ ey,
                              float* __restrict__ out) {
  const int b = blockIdx.x, lane = threadIdx.x;  // 64 threads
  float sxy = 0.f, sxx = 0.f, syy = 0.f;
#pragma unroll
  for (int i = 0; i < 10; i++) {
    const float x = ex[b * DMODEL + lane + 64 * i];
    const float y = ey[b * DMODEL + lane + 64 * i];
    sxy += x * y; sxx += x * x; syy += y * y;
  }
#pragma unroll
  for (int d = 1; d < 64; d <<= 1) {
    sxy += __shfl_xor(sxy, d); sxx += __shfl_xor(sxx, d); syy += __shfl_xor(syy, d);
  }
  if (lane == 0) {
    const float nx = fmaxf(sqrtf(sxx), 1e-8f);
    const float ny = fmaxf(sqrtf(syy), 1e-8f);
    out[b] = sxy / (nx * ny);
  }
}

// ---------------------------------------------------------------------------

extern "C" void kernel_launch(void* const* d_in, const int* in_sizes, int n_in,
                              void* d_out, int out_size, void* d_ws, size_t ws_size,
                              hipStream_t stream) {
  (void)in_sizes; (void)n_in; (void)out_size;
  const float* x    = (const float*)d_in[0];
  const float* y    = (const float*)d_in[3];
  const float* Wqkv = (const float*)d_in[6];
  const float* bqkv = (const float*)d_in[7];
  const float* Wo   = (const float*)d_in[8];
  const float* bo   = (const float*)d_in[9];
  const float* ln1g = (const float*)d_in[10];
  const float* ln1b = (const float*)d_in[11];
  const float* W1   = (const float*)d_in[12];
  const float* b1   = (const float*)d_in[13];
  const float* W2   = (const float*)d_in[14];
  const float* b2   = (const float*)d_in[15];
  const float* ln2g = (const float*)d_in[16];
  const float* ln2b = (const float*)d_in[17];
  const float* lneg = (const float*)d_in[18];
  const float* lneb = (const float*)d_in[19];
  const float* We   = (const float*)d_in[20];
  const float* be   = (const float*)d_in[21];

  auto algn = [](size_t b) { return (b + 255) & ~(size_t)255; };
  const size_t wbytes = algn((size_t)NLAYER * 3 * DMODEL * DMODEL * 2) +
                        algn((size_t)NLAYER * DMODEL * DMODEL * 2) +
                        2 * algn((size_t)NLAYER * FDIM * DMODEL * 2);
  auto actbytes = [&](size_t R) {
    return algn(R * DMODEL * 2) + algn(R * 3 * DMODEL * 2) + algn(R * FDIM * 2) +
           4 * algn((size_t)BDIM * DMODEL * 4);
  };
  const int NS = (wbytes + actbytes((size_t)2 * MROWS) <= ws_size) ? 2 : 1;
  const size_t R = (size_t)NS * MROWS;

  char* ws = (char*)d_ws;
  size_t off = 0;
  auto alloc = [&](size_t bytes) -> char* {
    char* p = ws + off;
    off += algn(bytes);
    return p;
  };
  _Float16* Wqkv_h = (_Float16*)alloc((size_t)NLAYER * 3 * DMODEL * DMODEL * 2);
  _Float16* Wo_h   = (_Float16*)alloc((size_t)NLAYER * DMODEL * DMODEL * 2);
  _Float16* W1_h   = (_Float16*)alloc((size_t)NLAYER * FDIM * DMODEL * 2);
  _Float16* W2_h   = (_Float16*)alloc((size_t)NLAYER * DMODEL * FDIM * 2);
  _Float16* h_h    = (_Float16*)alloc(R * DMODEL * 2);
  _Float16* qkv_h  = (_Float16*)alloc(R * 3 * DMODEL * 2);  // aliases tmp2
  _Float16* ff_h   = (_Float16*)alloc(R * FDIM * 2);        // aliases o_h
  float*    pooled = (float*)   alloc((size_t)BDIM * DMODEL * 4);
  float*    elnb   = (float*)   alloc((size_t)BDIM * DMODEL * 4);
  float*    exb    = (float*)   alloc((size_t)BDIM * DMODEL * 4);
  float*    eyb    = (float*)   alloc((size_t)BDIM * DMODEL * 4);
  if (off > ws_size) return;
  _Float16* tmp2 = qkv_h;    // split-K partials; qkv dead once attn has run
  _Float16* o_h  = ff_h;     // o dead before ff is written

  cvt_kernel<<<2048, 256, 0, stream>>>(Wqkv, Wqkv_h, NLAYER * 3 * DMODEL * DMODEL);
  cvt_kernel<<<2048, 256, 0, stream>>>(Wo,   Wo_h,   NLAYER * DMODEL * DMODEL);
  cvt_kernel<<<2048, 256, 0, stream>>>(W1,   W1_h,   NLAYER * FDIM * DMODEL);
  cvt_kernel<<<2048, 256, 0, stream>>>(W2,   W2_h,   NLAYER * DMODEL * FDIM);

  const float* seq_in[2] = {x, y};
  float* eouts[2] = {exb, eyb};
  const int Mr = (int)R;
  const size_t halfo = (size_t)Mr * DMODEL;

  for (int s0 = 0; s0 < 2; s0 += NS) {
    for (int s = 0; s < NS; s++)
      cvt_kernel<<<2048, 256, 0, stream>>>(
          seq_in[s0 + s], h_h + (size_t)s * MROWS * DMODEL, MROWS * DMODEL);
    for (int l = 0; l < NLAYER; l++) {
      gemm_bt<false, false, false><<<dim3(Mr / 128, 15), 256, 0, stream>>>(
          h_h, Wqkv_h + (size_t)l * 3 * DMODEL * DMODEL, bqkv + l * 3 * DMODEL,
          nullptr, qkv_h, Mr, 3 * DMODEL, DMODEL, DMODEL);
      attn_kernel<<<dim3(LSEQ / 64, NHEAD, Mr / LSEQ), 256, 0, stream>>>(qkv_h, o_h);
      gemm_bt<false, true, true><<<dim3(Mr / 128, 5, 2), 256, 0, stream>>>(
          o_h, Wo_h + (size_t)l * DMODEL * DMODEL, bo + l * DMODEL,
          h_h, tmp2, Mr, DMODEL, DMODEL / 2, DMODEL);
      ln_res2_kernel<<<Mr / 4, 256, 0, stream>>>(
          tmp2, tmp2 + halfo, ln1g + l * DMODEL, ln1b + l * DMODEL, h_h);
      gemm_bt<true, false, false><<<dim3(Mr / 128, 10), 256, 0, stream>>>(
          h_h, W1_h + (size_t)l * FDIM * DMODEL, b1 + l * FDIM,
          nullptr, ff_h, Mr, FDIM, DMODEL, DMODEL);
      gemm_bt<false, true, true><<<dim3(Mr / 128, 5, 2), 256, 0, stream>>>(
          ff_h, W2_h + (size_t)l * DMODEL * FDIM, b2 + l * DMODEL,
          h_h, tmp2, Mr, DMODEL, FDIM / 2, FDIM);
      ln_res2_kernel<<<Mr / 4, 256, 0, stream>>>(
          tmp2, tmp2 + halfo, ln2g + l * DMODEL, ln2b + l * DMODEL, h_h);
    }
    for (int s = 0; s < NS; s++) {
      const _Float16* hseq = h_h + (size_t)s * MROWS * DMODEL;
      zero_kernel<<<(BDIM * DMODEL + 255) / 256, 256, 0, stream>>>(pooled, BDIM * DMODEL);
      pool_kernel<<<dim3(BDIM, 32), 256, 0, stream>>>(hseq, pooled);
      lnvec_kernel<<<BDIM, 64, 0, stream>>>(pooled, lneg, lneb, elnb);
      embed_kernel<<<BDIM * DMODEL / 4, 256, 0, stream>>>(elnb, We, be, eouts[s0 + s]);
    }
  }
  cosine_kernel<<<BDIM, 64, 0, stream>>>(exb, eyb, (float*)d_out);
}

// Round 7
// 1797.368 us; speedup vs baseline: 1.0374x; 1.0374x over previous
//
#include <hip/hip_runtime.h>

// ---------------------------------------------------------------------------
// MaskedTransformerEmbeddingCosine on MI355X (gfx950)
// R6: register-staged GEMM K-loop (buffer_load -> VGPR -> ds_write, AITER
//     pattern). No LDS-DMA => compiler emits fine-grained vmcnt before the
//     ds_writes (after MFMA phase) instead of a forced vmcnt(0) drain before
//     the fragment reads. 2 LDS buffers (32 KB).
// ---------------------------------------------------------------------------

#define LSEQ   1024
#define DMODEL 640
#define NHEAD  10
#define DHEAD  64
#define NLAYER 6
#define BDIM   8
#define FDIM   1280
#define MROWS  (BDIM * LSEQ)

typedef __attribute__((ext_vector_type(8))) _Float16 half8;
typedef __attribute__((ext_vector_type(4))) float    floatx4;

// ---------------------------------------------------------------------------
// C = A(M,:) @ B(N,:)^T + bias [+ res] [relu]; row stride ld, K per z-slice.
// 128x128 tile, 4 waves each 64x64 (4x4 of 16x16x32), BK=32.
// Register staging: iter i loads tile i+1 into VGPRs right after the barrier,
// computes tile i from LDS, then ds_writes tile i+1 (vmcnt waits land here,
// one full compute phase after issue).
// ---------------------------------------------------------------------------
template <bool RELU, bool RESADD, bool SPLITK>
__global__ __launch_bounds__(256) void gemm_bt(const _Float16* __restrict__ A,
                                               const _Float16* __restrict__ Bw,
                                               const float* __restrict__ bias,
                                               const _Float16* __restrict__ res,
                                               _Float16* __restrict__ Cout,
                                               int M, int N, int K, int ld) {
  __shared__ _Float16 As[2][128 * 32];
  __shared__ _Float16 Bs[2][128 * 32];
  const int m0 = blockIdx.x * 128, n0 = blockIdx.y * 128;
  const int kz = SPLITK ? blockIdx.z : 0;
  const int tid = threadIdx.x;
  const int w = tid >> 6, lane = tid & 63;
  const int quad = lane >> 4, l16 = lane & 15;
  const int wm = w >> 1, wn = w & 1;

  floatx4 acc[4][4];
#pragma unroll
  for (int i = 0; i < 4; i++)
#pragma unroll
    for (int j = 0; j < 4; j++) acc[i][j] = (floatx4){0.f, 0.f, 0.f, 0.f};

  // staging map: lane -> row w*16+(lane>>2); k-chunk xor-swizzled in the row
  const int arow = w * 16 + (lane >> 2);
  const int kswz = ((lane & 3) ^ ((lane >> 3) & 3)) * 8;
  const _Float16* ag = A + (size_t)(m0 + arow) * ld + kz * K + kswz;
  const _Float16* bg = Bw + (size_t)(n0 + arow) * ld + kz * K + kswz;
  const size_t krows = (size_t)64 * ld;
  // LDS write slot for this lane (halves): row-major slot (lane&3), data is
  // global chunk (lane&3)^((row>>1)&3) -> matches fro below.
  const int wofs0 = (w * 16 + (lane >> 2)) * 32 + (lane & 3) * 8;
  const int wofs1 = wofs0 + 64 * 32;

  // fragment-read: row l16, chunk quad lives at slot quad^((l16>>1)&3)
  const int fro = l16 * 32 + ((quad ^ ((l16 >> 1) & 3)) * 8);

  const int nIter = K >> 5;
  // prologue: tile 0 -> regs -> buf 0
  {
    uint4 a0 = *(const uint4*)ag;
    uint4 a1 = *(const uint4*)(ag + krows);
    uint4 b0 = *(const uint4*)bg;
    uint4 b1 = *(const uint4*)(bg + krows);
    ag += 32; bg += 32;
    *(uint4*)&As[0][wofs0] = a0;
    *(uint4*)&As[0][wofs1] = a1;
    *(uint4*)&Bs[0][wofs0] = b0;
    *(uint4*)&Bs[0][wofs1] = b1;
  }

  for (int i = 0; i < nIter; i++) {
    __syncthreads();  // lgkm drain orders ds_writes; vmcnt already 0 here
    uint4 na0, na1, nb0, nb1;
    const bool pf = (i + 1 < nIter);
    if (pf) {  // issue next tile's loads NOW; consumed after the MFMA phase
      na0 = *(const uint4*)ag;
      na1 = *(const uint4*)(ag + krows);
      nb0 = *(const uint4*)bg;
      nb1 = *(const uint4*)(bg + krows);
      ag += 32; bg += 32;
    }
    const _Float16* as = As[i & 1];
    const _Float16* bs = Bs[i & 1];
    half8 af[4], bf[4];
#pragma unroll
    for (int mt = 0; mt < 4; mt++)
      af[mt] = *(const half8*)&as[(wm * 64 + mt * 16) * 32 + fro];
#pragma unroll
    for (int nt = 0; nt < 4; nt++)
      bf[nt] = *(const half8*)&bs[(wn * 64 + nt * 16) * 32 + fro];
#pragma unroll
    for (int mt = 0; mt < 4; mt++)
#pragma unroll
      for (int nt = 0; nt < 4; nt++)
        acc[mt][nt] = __builtin_amdgcn_mfma_f32_16x16x32_f16(af[mt], bf[nt], acc[mt][nt], 0, 0, 0);
    if (pf) {  // compiler inserts fine-grained vmcnt right before these
      _Float16* asn = As[(i + 1) & 1];
      _Float16* bsn = Bs[(i + 1) & 1];
      *(uint4*)&asn[wofs0] = na0;
      *(uint4*)&asn[wofs1] = na1;
      *(uint4*)&bsn[wofs0] = nb0;
      *(uint4*)&bsn[wofs1] = nb1;
    }
  }

  const bool lead = (!SPLITK) || (kz == 0);
  _Float16* outp = Cout + (SPLITK ? (size_t)kz * ((size_t)M * N) : 0);
  float bv[4];
#pragma unroll
  for (int nt = 0; nt < 4; nt++)
    bv[nt] = lead ? bias[n0 + wn * 64 + nt * 16 + l16] : 0.f;
#pragma unroll
  for (int mt = 0; mt < 4; mt++) {
#pragma unroll
    for (int reg = 0; reg < 4; reg++) {
      const int row = m0 + wm * 64 + mt * 16 + quad * 4 + reg;
#pragma unroll
      for (int nt = 0; nt < 4; nt++) {
        const int col = n0 + wn * 64 + nt * 16 + l16;
        float v = acc[mt][nt][reg] + bv[nt];
        if (RESADD) { if (lead) v += (float)res[(size_t)row * N + col]; }
        if (RELU) v = fmaxf(v, 0.f);
        outp[(size_t)row * N + col] = (_Float16)v;
      }
    }
  }
}

// ---------------------------------------------------------------------------
// Banded attention: one block per (64-query tile, head, row-batch of 1024).
// ---------------------------------------------------------------------------
__global__ __launch_bounds__(256) void attn_kernel(const _Float16* __restrict__ qkv,
                                                   _Float16* __restrict__ o) {
  __shared__ _Float16 Qs[64 * 72];
  __shared__ _Float16 KP[192 * 72];   // K tiles; later reused as P (64 x 200)
  __shared__ _Float16 Vt[64 * 200];   // V transposed
  const int qb = blockIdx.x, h = blockIdx.y, b = blockIdx.z;
  const int q0 = qb * 64;
  const int kc0 = (q0 - 64 > 0) ? q0 - 64 : 0;
  const int kend = (q0 + 128 < LSEQ) ? q0 + 128 : LSEQ;
  const int cnt = kend - kc0;
  const int tid = threadIdx.x;

  for (int c = tid; c < 512; c += 256) {
    const int row = c >> 3, ch = c & 7;
    *(uint4*)&Qs[row * 72 + ch * 8] =
        *(const uint4*)(qkv + (size_t)(b * LSEQ + q0 + row) * (3 * DMODEL) + h * DHEAD + ch * 8);
  }
  for (int c = tid; c < 1536; c += 256) {
    const int row = c >> 3, ch = c & 7;
    uint4 v = {0u, 0u, 0u, 0u};
    if (row < cnt)
      v = *(const uint4*)(qkv + (size_t)(b * LSEQ + kc0 + row) * (3 * DMODEL) + DMODEL + h * DHEAD + ch * 8);
    *(uint4*)&KP[row * 72 + ch * 8] = v;
  }
  for (int c = tid; c < 1536; c += 256) {
    const int row = c >> 3, ch = c & 7;
    uint4 v = {0u, 0u, 0u, 0u};
    if (row < cnt)
      v = *(const uint4*)(qkv + (size_t)(b * LSEQ + kc0 + row) * (3 * DMODEL) + 2 * DMODEL + h * DHEAD + ch * 8);
    _Float16 tmp[8];
    *(uint4*)tmp = v;
#pragma unroll
    for (int jj = 0; jj < 8; jj++) Vt[(ch * 8 + jj) * 200 + row] = tmp[jj];
  }
  __syncthreads();

  const int w = tid >> 6, lane = tid & 63, quad = lane >> 4, l16 = lane & 15;

  floatx4 sacc[12];
#pragma unroll
  for (int i = 0; i < 12; i++) sacc[i] = (floatx4){0.f, 0.f, 0.f, 0.f};
#pragma unroll
  for (int ks = 0; ks < 2; ks++) {
    const half8 qf = *(const half8*)&Qs[(w * 16 + l16) * 72 + ks * 32 + quad * 8];
#pragma unroll
    for (int nt = 0; nt < 12; nt++) {
      const half8 kf = *(const half8*)&KP[(nt * 16 + l16) * 72 + ks * 32 + quad * 8];
      sacc[nt] = __builtin_amdgcn_mfma_f32_16x16x32_f16(qf, kf, sacc[nt], 0, 0, 0);
    }
  }
  __syncthreads();

#pragma unroll
  for (int r = 0; r < 4; r++) {
    const int qi = q0 + w * 16 + quad * 4 + r;
    float sv[12];
    float m = -1e30f;
#pragma unroll
    for (int nt = 0; nt < 12; nt++) {
      const int key = kc0 + nt * 16 + l16;
      const bool ok = (key >= qi - 64) && (key <= qi + 64) && (key < LSEQ);
      const float s = ok ? sacc[nt][r] * 0.125f : -1e30f;
      sv[nt] = s;
      m = fmaxf(m, s);
    }
#pragma unroll
    for (int d = 1; d < 16; d <<= 1) m = fmaxf(m, __shfl_xor(m, d));
    float sum = 0.f;
#pragma unroll
    for (int nt = 0; nt < 12; nt++) {
      const float p = __expf(sv[nt] - m);
      sv[nt] = p;
      sum += p;
    }
#pragma unroll
    for (int d = 1; d < 16; d <<= 1) sum += __shfl_xor(sum, d);
    const float inv = 1.f / sum;
    _Float16* Pr = &KP[(w * 16 + quad * 4 + r) * 200];
#pragma unroll
    for (int nt = 0; nt < 12; nt++) Pr[nt * 16 + l16] = (_Float16)(sv[nt] * inv);
  }
  __syncthreads();

  floatx4 oacc[4];
#pragma unroll
  for (int i = 0; i < 4; i++) oacc[i] = (floatx4){0.f, 0.f, 0.f, 0.f};
#pragma unroll
  for (int ks = 0; ks < 6; ks++) {
    const half8 pf = *(const half8*)&KP[(w * 16 + l16) * 200 + ks * 32 + quad * 8];
#pragma unroll
    for (int nt = 0; nt < 4; nt++) {
      const half8 vf = *(const half8*)&Vt[(nt * 16 + l16) * 200 + ks * 32 + quad * 8];
      oacc[nt] = __builtin_amdgcn_mfma_f32_16x16x32_f16(pf, vf, oacc[nt], 0, 0, 0);
    }
  }
#pragma unroll
  for (int nt = 0; nt < 4; nt++)
#pragma unroll
    for (int reg = 0; reg < 4; reg++) {
      const int row = q0 + w * 16 + quad * 4 + reg;
      const int col = h * DHEAD + nt * 16 + l16;
      o[(size_t)(b * LSEQ + row) * DMODEL + col] = (_Float16)oacc[nt][reg];
    }
}

// ---------------------------------------------------------------------------
// h = LayerNorm(s0 + s1) — fp16 split-K partials in, fp16 out. One wave/row.
// ---------------------------------------------------------------------------
__global__ __launch_bounds__(256) void ln_res2_kernel(const _Float16* __restrict__ s0,
                                                      const _Float16* __restrict__ s1,
                                                      const float* __restrict__ g,
                                                      const float* __restrict__ bta,
                                                      _Float16* __restrict__ hh) {
  const int row = blockIdx.x * 4 + (threadIdx.x >> 6);
  const int lane = threadIdx.x & 63;
  const _Float16* p0 = s0 + (size_t)row * DMODEL;
  const _Float16* p1 = s1 + (size_t)row * DMODEL;
  float v[10], s = 0.f, ss = 0.f;
#pragma unroll
  for (int i = 0; i < 10; i++) {
    const float x = (float)p0[lane + 64 * i] + (float)p1[lane + 64 * i];
    v[i] = x; s += x; ss += x * x;
  }
#pragma unroll
  for (int d = 1; d < 64; d <<= 1) { s += __shfl_xor(s, d); ss += __shfl_xor(ss, d); }
  const float mean = s * (1.f / DMODEL);
  const float var = ss * (1.f / DMODEL) - mean * mean;
  const float rstd = rsqrtf(var + 1e-5f);
#pragma unroll
  for (int i = 0; i < 10; i++) {
    const int d = lane + 64 * i;
    hh[(size_t)row * DMODEL + d] = (_Float16)((v[i] - mean) * rstd * g[d] + bta[d]);
  }
}

__global__ void cvt_kernel(const float* __restrict__ s, _Float16* __restrict__ d, int n) {
  int i = blockIdx.x * blockDim.x + threadIdx.x;
  const int stride = gridDim.x * blockDim.x;
  for (; i < n; i += stride) d[i] = (_Float16)s[i];
}

__global__ void zero_kernel(float* __restrict__ p, int n) {
  const int i = blockIdx.x * blockDim.x + threadIdx.x;
  if (i < n) p[i] = 0.f;
}

__global__ void pool_kernel(const _Float16* __restrict__ h, float* __restrict__ pooled) {
  const int b = blockIdx.x, chunk = blockIdx.y;  // 32 rows per chunk
  for (int d = threadIdx.x; d < DMODEL; d += 256) {
    float s = 0.f;
    const _Float16* p = h + ((size_t)b * LSEQ + chunk * 32) * DMODEL + d;
#pragma unroll 4
    for (int l = 0; l < 32; l++) s += (float)p[(size_t)l * DMODEL];
    atomicAdd(&pooled[b * DMODEL + d], s);
  }
}

__global__ void lnvec_kernel(const float* __restrict__ pooled, const float* __restrict__ g,
                             const float* __restrict__ bta, float* __restrict__ eln) {
  const int b = blockIdx.x, lane = threadIdx.x;  // 64 threads
  float v[10], s = 0.f, ss = 0.f;
#pragma unroll
  for (int i = 0; i < 10; i++) {
    const float x = pooled[b * DMODEL + lane + 64 * i];
    v[i] = x; s += x; ss += x * x;
  }
#pragma unroll
  for (int d = 1; d < 64; d <<= 1) { s += __shfl_xor(s, d); ss += __shfl_xor(ss, d); }
  const float mean = s * (1.f / DMODEL);
  const float var = ss * (1.f / DMODEL) - mean * mean;
  const float rstd = rsqrtf(var + 1e-5f);
#pragma unroll
  for (int i = 0; i < 10; i++) {
    const int d = lane + 64 * i;
    eln[b * DMODEL + d] = (v[i] - mean) * rstd * g[d] + bta[d];
  }
}

// one wave per output element
__global__ __launch_bounds__(256) void embed_kernel(const float* __restrict__ eln,
                                                    const float* __restrict__ We,
                                                    const float* __restrict__ be,
                                                    float* __restrict__ e) {
  const int gw = (blockIdx.x << 2) + (threadIdx.x >> 6);
  const int lane = threadIdx.x & 63;
  const int b = gw / DMODEL, n = gw % DMODEL;
  const float* wr = We + (size_t)n * DMODEL;
  const float* er = eln + (size_t)b * DMODEL;
  float s = 0.f;
#pragma unroll
  for (int i = 0; i < 10; i++) s += wr[lane + 64 * i] * er[lane + 64 * i];
#pragma unroll
  for (int d = 1; d < 64; d <<= 1) s += __shfl_xor(s, d);
  if (lane == 0) e[(size_t)b * DMODEL + n] = fmaxf(s + be[n], 0.f);
}

__global__ void cosine_kernel(const float* __restrict__ ex, const float* __restrict__ ey,
                              float* __restrict__ out) {
  const int b = blockIdx.x, lane = threadIdx.x;  // 64 threads
  float sxy = 0.f, sxx = 0.f, syy = 0.f;
#pragma unroll
  for (int i = 0; i < 10; i++) {
    const float x = ex[b * DMODEL + lane + 64 * i];
    const float y = ey[b * DMODEL + lane + 64 * i];
    sxy += x * y; sxx += x * x; syy += y * y;
  }
#pragma unroll
  for (int d = 1; d < 64; d <<= 1) {
    sxy += __shfl_xor(sxy, d); sxx += __shfl_xor(sxx, d); syy += __shfl_xor(syy, d);
  }
  if (lane == 0) {
    const float nx = fmaxf(sqrtf(sxx), 1e-8f);
    const float ny = fmaxf(sqrtf(syy), 1e-8f);
    out[b] = sxy / (nx * ny);
  }
}

// ---------------------------------------------------------------------------

extern "C" void kernel_launch(void* const* d_in, const int* in_sizes, int n_in,
                              void* d_out, int out_size, void* d_ws, size_t ws_size,
                              hipStream_t stream) {
  (void)in_sizes; (void)n_in; (void)out_size;
  const float* x    = (const float*)d_in[0];
  const float* y    = (const float*)d_in[3];
  const float* Wqkv = (const float*)d_in[6];
  const float* bqkv = (const float*)d_in[7];
  const float* Wo   = (const float*)d_in[8];
  const float* bo   = (const float*)d_in[9];
  const float* ln1g = (const float*)d_in[10];
  const float* ln1b = (const float*)d_in[11];
  const float* W1   = (const float*)d_in[12];
  const float* b1   = (const float*)d_in[13];
  const float* W2   = (const float*)d_in[14];
  const float* b2   = (const float*)d_in[15];
  const float* ln2g = (const float*)d_in[16];
  const float* ln2b = (const float*)d_in[17];
  const float* lneg = (const float*)d_in[18];
  const float* lneb = (const float*)d_in[19];
  const float* We   = (const float*)d_in[20];
  const float* be   = (const float*)d_in[21];

  auto algn = [](size_t b) { return (b + 255) & ~(size_t)255; };
  const size_t wbytes = algn((size_t)NLAYER * 3 * DMODEL * DMODEL * 2) +
                        algn((size_t)NLAYER * DMODEL * DMODEL * 2) +
                        2 * algn((size_t)NLAYER * FDIM * DMODEL * 2);
  auto actbytes = [&](size_t R) {
    return algn(R * DMODEL * 2) + algn(R * 3 * DMODEL * 2) + algn(R * FDIM * 2) +
           4 * algn((size_t)BDIM * DMODEL * 4);
  };
  const int NS = (wbytes + actbytes((size_t)2 * MROWS) <= ws_size) ? 2 : 1;
  const size_t R = (size_t)NS * MROWS;

  char* ws = (char*)d_ws;
  size_t off = 0;
  auto alloc = [&](size_t bytes) -> char* {
    char* p = ws + off;
    off += algn(bytes);
    return p;
  };
  _Float16* Wqkv_h = (_Float16*)alloc((size_t)NLAYER * 3 * DMODEL * DMODEL * 2);
  _Float16* Wo_h   = (_Float16*)alloc((size_t)NLAYER * DMODEL * DMODEL * 2);
  _Float16* W1_h   = (_Float16*)alloc((size_t)NLAYER * FDIM * DMODEL * 2);
  _Float16* W2_h   = (_Float16*)alloc((size_t)NLAYER * DMODEL * FDIM * 2);
  _Float16* h_h    = (_Float16*)alloc(R * DMODEL * 2);
  _Float16* qkv_h  = (_Float16*)alloc(R * 3 * DMODEL * 2);  // aliases tmp2
  _Float16* ff_h   = (_Float16*)alloc(R * FDIM * 2);        // aliases o_h
  float*    pooled = (float*)   alloc((size_t)BDIM * DMODEL * 4);
  float*    elnb   = (float*)   alloc((size_t)BDIM * DMODEL * 4);
  float*    exb    = (float*)   alloc((size_t)BDIM * DMODEL * 4);
  float*    eyb    = (float*)   alloc((size_t)BDIM * DMODEL * 4);
  if (off > ws_size) return;
  _Float16* tmp2 = qkv_h;    // split-K partials; qkv dead once attn has run
  _Float16* o_h  = ff_h;     // o dead before ff is written

  cvt_kernel<<<2048, 256, 0, stream>>>(Wqkv, Wqkv_h, NLAYER * 3 * DMODEL * DMODEL);
  cvt_kernel<<<2048, 256, 0, stream>>>(Wo,   Wo_h,   NLAYER * DMODEL * DMODEL);
  cvt_kernel<<<2048, 256, 0, stream>>>(W1,   W1_h,   NLAYER * FDIM * DMODEL);
  cvt_kernel<<<2048, 256, 0, stream>>>(W2,   W2_h,   NLAYER * DMODEL * FDIM);

  const float* seq_in[2] = {x, y};
  float* eouts[2] = {exb, eyb};
  const int Mr = (int)R;
  const size_t halfo = (size_t)Mr * DMODEL;

  for (int s0 = 0; s0 < 2; s0 += NS) {
    for (int s = 0; s < NS; s++)
      cvt_kernel<<<2048, 256, 0, stream>>>(
          seq_in[s0 + s], h_h + (size_t)s * MROWS * DMODEL, MROWS * DMODEL);
    for (int l = 0; l < NLAYER; l++) {
      gemm_bt<false, false, false><<<dim3(Mr / 128, 15), 256, 0, stream>>>(
          h_h, Wqkv_h + (size_t)l * 3 * DMODEL * DMODEL, bqkv + l * 3 * DMODEL,
          nullptr, qkv_h, Mr, 3 * DMODEL, DMODEL, DMODEL);
      attn_kernel<<<dim3(LSEQ / 64, NHEAD, Mr / LSEQ), 256, 0, stream>>>(qkv_h, o_h);
      gemm_bt<false, true, true><<<dim3(Mr / 128, 5, 2), 256, 0, stream>>>(
          o_h, Wo_h + (size_t)l * DMODEL * DMODEL, bo + l * DMODEL,
          h_h, tmp2, Mr, DMODEL, DMODEL / 2, DMODEL);
      ln_res2_kernel<<<Mr / 4, 256, 0, stream>>>(
          tmp2, tmp2 + halfo, ln1g + l * DMODEL, ln1b + l * DMODEL, h_h);
      gemm_bt<true, false, false><<<dim3(Mr / 128, 10), 256, 0, stream>>>(
          h_h, W1_h + (size_t)l * FDIM * DMODEL, b1 + l * FDIM,
          nullptr, ff_h, Mr, FDIM, DMODEL, DMODEL);
      gemm_bt<false, true, true><<<dim3(Mr / 128, 5, 2), 256, 0, stream>>>(
          ff_h, W2_h + (size_t)l * DMODEL * FDIM, b2 + l * DMODEL,
          h_h, tmp2, Mr, DMODEL, FDIM / 2, FDIM);
      ln_res2_kernel<<<Mr / 4, 256, 0, stream>>>(
          tmp2, tmp2 + halfo, ln2g + l * DMODEL, ln2b + l * DMODEL, h_h);
    }
    for (int s = 0; s < NS; s++) {
      const _Float16* hseq = h_h + (size_t)s * MROWS * DMODEL;
      zero_kernel<<<(BDIM * DMODEL + 255) / 256, 256, 0, stream>>>(pooled, BDIM * DMODEL);
      pool_kernel<<<dim3(BDIM, 32), 256, 0, stream>>>(hseq, pooled);
      lnvec_kernel<<<BDIM, 64, 0, stream>>>(pooled, lneg, lneb, elnb);
      embed_kernel<<<BDIM * DMODEL / 4, 256, 0, stream>>>(elnb, We, be, eouts[s0 + s]);
    }
  }
  cosine_kernel<<<BDIM, 64, 0, stream>>>(exb, eyb, (float*)d_out);
}